// Round 2
// baseline (838.984 us; speedup 1.0000x reference)
//
#include <hip/hip_runtime.h>

// GCN_85804856639970: 2-layer GCN + FC head on MI355X.
// N=50000, E=800000, D_IN=128, D_HID=128, D_OUT=64.
// All float tensors are fp32 (reference dtype); edge_index arrives as int32.
//
// Math: dinv = rsqrt(in_deg+1); per layer:
//   hs = (X@W) * dinv[row]                (pre-scale)
//   acc[i] = hs[i] + sum_{src->i} hs[src] (self-loop = accumulator init)
//   h = relu(dinv[i]*acc[i] + b)          (post-scale)
// Final: out = h2 @ fc_W + fc_b.

__global__ void k_init_deg(float* __restrict__ deg, int n) {
    int i = blockIdx.x * blockDim.x + threadIdx.x;
    if (i < n) deg[i] = 1.0f;  // self-loop
}

__global__ void k_count_deg(const int* __restrict__ dst, int e, float* __restrict__ deg) {
    int i = blockIdx.x * blockDim.x + threadIdx.x;
    if (i < e) atomicAdd(&deg[dst[i]], 1.0f);
}

__global__ void k_rsqrt(float* __restrict__ deg, int n) {
    int i = blockIdx.x * blockDim.x + threadIdx.x;
    if (i < n) deg[i] = rsqrtf(deg[i]);  // deg >= 1 always
}

// One block per row; M threads (one per output feature). Row staged in LDS.
// Writes hs = (X@W)*dinv[row] and acc = hs (self-loop init).
template <int K, int M>
__global__ void k_gemm_scale(const float* __restrict__ X,
                             const float* __restrict__ W,
                             const float* __restrict__ dinv,
                             float* __restrict__ hs, float* __restrict__ acc, int n) {
    __shared__ float xrow[K];
    int row = blockIdx.x;
    if (row >= n) return;
    int j = threadIdx.x;  // 0..M-1
    for (int k = j; k < K; k += M) xrow[k] = X[(size_t)row * K + k];
    __syncthreads();
    float a = 0.0f;
#pragma unroll
    for (int k = 0; k < K; ++k) a += xrow[k] * W[k * M + j];
    float v = a * dinv[row];
    hs[(size_t)row * M + j] = v;
    acc[(size_t)row * M + j] = v;
}

// One thread per (edge, feature). Lanes cover consecutive features of the
// same edge -> coalesced hs read and coalesced atomic destination.
template <int M>
__global__ void k_scatter(const int* __restrict__ src, const int* __restrict__ dst,
                          const float* __restrict__ hs, float* __restrict__ acc, int e) {
    unsigned long long t = (unsigned long long)blockIdx.x * blockDim.x + threadIdx.x;
    int eidx = (int)(t / M);
    int f = (int)(t % M);
    if (eidx >= e) return;
    int s = src[eidx];
    int d = dst[eidx];
    atomicAdd(&acc[(size_t)d * M + f], hs[(size_t)s * M + f]);
}

// h = relu(dinv[row]*acc + b[f]), written in place over acc.
template <int M>
__global__ void k_finalize(float* __restrict__ acc, const float* __restrict__ dinv,
                           const float* __restrict__ b, int n) {
    int t = blockIdx.x * blockDim.x + threadIdx.x;
    if (t >= n * M) return;
    int row = t / M;
    int f = t % M;
    float v = dinv[row] * acc[t] + b[f];
    acc[t] = fmaxf(v, 0.0f);
}

// out[row,:] = H[row,:] @ W (64x64) + b. One block (64 thr) per row.
__global__ void k_gemm_out(const float* __restrict__ H,
                           const float* __restrict__ W,
                           const float* __restrict__ b,
                           float* __restrict__ out, int n) {
    __shared__ float hrow[64];
    int row = blockIdx.x;
    if (row >= n) return;
    int j = threadIdx.x;  // 0..63
    hrow[j] = H[(size_t)row * 64 + j];
    __syncthreads();
    float a = b[j];
#pragma unroll
    for (int k = 0; k < 64; ++k) a += hrow[k] * W[k * 64 + j];
    out[(size_t)row * 64 + j] = a;
}

extern "C" void kernel_launch(void* const* d_in, const int* in_sizes, int n_in,
                              void* d_out, int out_size, void* d_ws, size_t ws_size,
                              hipStream_t stream) {
    const float* x   = (const float*)d_in[0];
    const int*   ei  = (const int*)d_in[1];
    const float* W1  = (const float*)d_in[2];
    const float* b1  = (const float*)d_in[3];
    const float* W2  = (const float*)d_in[4];
    const float* b2  = (const float*)d_in[5];
    const float* fcW = (const float*)d_in[6];
    const float* fcb = (const float*)d_in[7];
    float* out = (float*)d_out;

    const int N = in_sizes[0] / 128;
    const int E = in_sizes[1] / 2;
    const int* src = ei;       // edge_index[0]
    const int* dst = ei + E;   // edge_index[1]

    // Workspace (floats): deg[N] | bufA[N*128] | bufB[N*128]
    // layer1: hs1=bufA, acc1=bufB
    // layer2: X=acc1(bufB), hs2=bufA[0:N*64], acc2=bufA[N*64:N*128]
    // Total: N*(1+256)*4 bytes = ~51.4 MB.
    float* deg  = (float*)d_ws;
    float* bufA = deg + N;
    float* bufB = bufA + (size_t)N * 128;
    float* hs1  = bufA;
    float* acc1 = bufB;
    float* hs2  = bufA;
    float* acc2 = bufA + (size_t)N * 64;

    const int B = 256;

    // degree + dinv
    k_init_deg<<<(N + B - 1) / B, B, 0, stream>>>(deg, N);
    k_count_deg<<<(E + B - 1) / B, B, 0, stream>>>(dst, E, deg);
    k_rsqrt<<<(N + B - 1) / B, B, 0, stream>>>(deg, N);

    // Layer 1: 128 -> 128
    k_gemm_scale<128, 128><<<N, 128, 0, stream>>>(x, W1, deg, hs1, acc1, N);
    {
        unsigned long long total = (unsigned long long)E * 128ull;
        k_scatter<128><<<(unsigned)((total + B - 1) / B), B, 0, stream>>>(src, dst, hs1, acc1, E);
    }
    k_finalize<128><<<(N * 128 + B - 1) / B, B, 0, stream>>>(acc1, deg, b1, N);

    // Layer 2: 128 -> 64 (X = acc1 in bufB; hs2/acc2 reuse bufA)
    k_gemm_scale<128, 64><<<N, 64, 0, stream>>>(acc1, W2, deg, hs2, acc2, N);
    {
        unsigned long long total = (unsigned long long)E * 64ull;
        k_scatter<64><<<(unsigned)((total + B - 1) / B), B, 0, stream>>>(src, dst, hs2, acc2, E);
    }
    k_finalize<64><<<(N * 64 + B - 1) / B, B, 0, stream>>>(acc2, deg, b2, N);

    // FC head: 64 -> 64
    k_gemm_out<<<N, 64, 0, stream>>>(acc2, fcW, fcb, out, N);
}

// Round 3
// 662.516 us; speedup vs baseline: 1.2664x; 1.2664x over previous
//
#include <hip/hip_runtime.h>
#include <hip/hip_bf16.h>

// GCN_85804856639970 — 2-layer GCN + FC head, MI355X.
// N=50000, E=800000, 128->128->64, head 64x64. fp32 in/out, edge_index int32.
//
// R3: CSR-gather aggregation (no atomics in hot path), tiled GEMMs.
//   dinv = rsqrt(in_deg+1)
//   hs = (X@W)*dinv[row]                      (pre-scale fused in GEMM)
//   h  = relu(dinv[i]*(hs[i] + sum_nbr hs) + b)  (gather, fused epilogue)
//   out = h2@fcW + fcb

// ---------------- CSR build ----------------

__global__ void k_zero_int(int* __restrict__ p, int n) {
    int i = blockIdx.x * blockDim.x + threadIdx.x;
    if (i < n) p[i] = 0;
}

__global__ void k_count(const int* __restrict__ dst, int e, int* __restrict__ degi) {
    int i = blockIdx.x * blockDim.x + threadIdx.x;
    if (i < e) atomicAdd(&degi[dst[i]], 1);
}

// Per-256-chunk inclusive scan of degi -> rowptr[i+1] (partial), blocksum[b].
__global__ void k_scan1(const int* __restrict__ degi, int* __restrict__ rowptr,
                        int* __restrict__ blocksum, int n) {
    __shared__ int s[256];
    int tid = threadIdx.x;
    int i = blockIdx.x * 256 + tid;
    s[tid] = (i < n) ? degi[i] : 0;
    __syncthreads();
#pragma unroll
    for (int off = 1; off < 256; off <<= 1) {
        int t = (tid >= off) ? s[tid - off] : 0;
        __syncthreads();
        s[tid] += t;
        __syncthreads();
    }
    if (i < n) rowptr[i + 1] = s[tid];
    if (tid == 255) blocksum[blockIdx.x] = s[255];
}

// Single block scans the (<=256) block sums in place (inclusive).
__global__ void k_scan2(int* __restrict__ blocksum, int nb) {
    __shared__ int s[256];
    int tid = threadIdx.x;
    s[tid] = (tid < nb) ? blocksum[tid] : 0;
    __syncthreads();
#pragma unroll
    for (int off = 1; off < 256; off <<= 1) {
        int t = (tid >= off) ? s[tid - off] : 0;
        __syncthreads();
        s[tid] += t;
        __syncthreads();
    }
    if (tid < nb) blocksum[tid] = s[tid];
}

// Finalize rowptr (add block offsets), derive cursor (exclusive start) and dinv.
__global__ void k_scan3(int* __restrict__ rowptr, const int* __restrict__ blocksum,
                        const int* __restrict__ degi, int* __restrict__ cursor,
                        float* __restrict__ dinv, int n) {
    int i = blockIdx.x * blockDim.x + threadIdx.x;
    if (i >= n) return;
    int off = (blockIdx.x > 0) ? blocksum[blockIdx.x - 1] : 0;
    int incl = rowptr[i + 1] + off;
    rowptr[i + 1] = incl;
    cursor[i] = incl - degi[i];
    dinv[i] = rsqrtf((float)degi[i] + 1.0f);
    if (i == 0) rowptr[0] = 0;
}

__global__ void k_fill(const int* __restrict__ src, const int* __restrict__ dst, int e,
                       int* __restrict__ cursor, unsigned short* __restrict__ col) {
    int i = blockIdx.x * blockDim.x + threadIdx.x;
    if (i >= e) return;
    int d = dst[i];
    int pos = atomicAdd(&cursor[d], 1);
    col[pos] = (unsigned short)src[i];
}

// ---------------- Tiled GEMM ----------------
// Block: 256 threads, R=16 rows per block. G = 256/M row-groups, RT = R/G rows/thread.
// MODE 0: out[row] = acc * dinv[row]   (layer GEMM, pre-scale)
// MODE 1: out[row] = acc + bias[j]     (FC head)
template <int K, int M, int R, int MODE, typename TIN>
__global__ void k_gemm(const TIN* __restrict__ X, const float* __restrict__ W,
                       const float* __restrict__ dinv, const float* __restrict__ bias,
                       float* __restrict__ out, int n) {
    constexpr int G = 256 / M;
    constexpr int RT = R / G;
    __shared__ float xs[R * (K + 1)];
    int tid = threadIdx.x;
    int base = blockIdx.x * R;

    for (int idx = tid; idx < R * K; idx += 256) {
        int r = idx / K, k = idx - r * K;
        int row = base + r;
        xs[r * (K + 1) + k] = (row < n) ? (float)X[(size_t)row * K + k] : 0.0f;
    }
    __syncthreads();

    int j = tid % M;
    int g = tid / M;
    float acc[RT];
#pragma unroll
    for (int r = 0; r < RT; ++r) acc[r] = 0.0f;

    for (int k = 0; k < K; ++k) {
        float w = W[(size_t)k * M + j];
#pragma unroll
        for (int r = 0; r < RT; ++r)
            acc[r] += xs[(g * RT + r) * (K + 1) + k] * w;
    }

#pragma unroll
    for (int r = 0; r < RT; ++r) {
        int row = base + g * RT + r;
        if (row < n) {
            float v = (MODE == 0) ? acc[r] * dinv[row] : acc[r] + bias[j];
            out[(size_t)row * M + j] = v;
        }
    }
}

// ---------------- CSR aggregation (wave per node) ----------------
// out[i] = relu(dinv[i]*(hs[i] + sum_{c in nbr(i)} hs[c]) + bias)
// M=128: lane holds float2; M=64: lane holds float. TOUT = bf16 or float.
template <int M, typename TOUT>
__global__ void k_agg(const int* __restrict__ rowptr, const unsigned short* __restrict__ col,
                      const float* __restrict__ hs, const float* __restrict__ dinv,
                      const float* __restrict__ bias, TOUT* __restrict__ out, int n) {
    int wave = threadIdx.x >> 6;          // 4 waves/block
    int lane = threadIdx.x & 63;
    int node = blockIdx.x * 4 + wave;
    if (node >= n) return;

    int beg = rowptr[node];
    int end = rowptr[node + 1];
    float di = dinv[node];

    if (M == 128) {
        const float2* hp = (const float2*)hs;
        float2 a0 = hp[(size_t)node * 64 + lane];   // self-loop init
        float2 a1 = make_float2(0.0f, 0.0f);
        int i = beg;
        for (; i + 1 < end; i += 2) {
            int c0 = col[i], c1 = col[i + 1];
            float2 v0 = hp[(size_t)c0 * 64 + lane];
            float2 v1 = hp[(size_t)c1 * 64 + lane];
            a0.x += v0.x; a0.y += v0.y;
            a1.x += v1.x; a1.y += v1.y;
        }
        if (i < end) {
            int c0 = col[i];
            float2 v0 = hp[(size_t)c0 * 64 + lane];
            a0.x += v0.x; a0.y += v0.y;
        }
        float vx = fmaxf(di * (a0.x + a1.x) + bias[2 * lane], 0.0f);
        float vy = fmaxf(di * (a0.y + a1.y) + bias[2 * lane + 1], 0.0f);
        if constexpr (sizeof(TOUT) == 2) {
            __hip_bfloat162 o;
            o.x = __float2bfloat16(vx);
            o.y = __float2bfloat16(vy);
            ((__hip_bfloat162*)out)[(size_t)node * 64 + lane] = o;
        } else {
            float2 o = make_float2(vx, vy);
            ((float2*)out)[(size_t)node * 64 + lane] = o;
        }
    } else {  // M == 64
        float a0 = hs[(size_t)node * 64 + lane];
        float a1 = 0.0f;
        int i = beg;
        for (; i + 1 < end; i += 2) {
            int c0 = col[i], c1 = col[i + 1];
            a0 += hs[(size_t)c0 * 64 + lane];
            a1 += hs[(size_t)c1 * 64 + lane];
        }
        if (i < end) a0 += hs[(size_t)col[i] * 64 + lane];
        float v = fmaxf(di * (a0 + a1) + bias[lane], 0.0f);
        out[(size_t)node * 64 + lane] = (TOUT)v;
    }
}

// ---------------- launch ----------------

extern "C" void kernel_launch(void* const* d_in, const int* in_sizes, int n_in,
                              void* d_out, int out_size, void* d_ws, size_t ws_size,
                              hipStream_t stream) {
    const float* x   = (const float*)d_in[0];
    const int*   ei  = (const int*)d_in[1];
    const float* W1  = (const float*)d_in[2];
    const float* b1  = (const float*)d_in[3];
    const float* W2  = (const float*)d_in[4];
    const float* b2  = (const float*)d_in[5];
    const float* fcW = (const float*)d_in[6];
    const float* fcb = (const float*)d_in[7];
    float* out = (float*)d_out;

    const int N = in_sizes[0] / 128;
    const int E = in_sizes[1] / 2;
    const int* src = ei;
    const int* dst = ei + E;

    // ---- workspace carve (16B-aligned), peak ~41 MB ----
    auto align16 = [](size_t v) { return (v + 15) & ~(size_t)15; };
    char* p = (char*)d_ws;
    int* rowptr = (int*)p;             p += align16(sizeof(int) * (N + 1));
    unsigned short* col = (unsigned short*)p;  p += align16(sizeof(unsigned short) * E);
    float* dinv = (float*)p;           p += align16(sizeof(float) * N);
    int* degi = (int*)p;               p += align16(sizeof(int) * N);
    int* cursor = (int*)p;             p += align16(sizeof(int) * N);
    int* blocksum = (int*)p;           p += align16(sizeof(int) * 256);
    float* bufA = (float*)p;           p += align16(sizeof(float) * (size_t)N * 128);  // hs1; later hs2|h2
    __hip_bfloat16* h1 = (__hip_bfloat16*)p;   // bf16 N*128 = 12.8 MB

    float* hs1 = bufA;
    float* hs2 = bufA;                         // reuses hs1 (dead after agg1)
    float* h2  = bufA + (size_t)N * 64;        // second half of bufA

    const int B = 256;
    const int nb = (N + 255) / 256;

    // CSR build
    k_zero_int<<<(N + B - 1) / B, B, 0, stream>>>(degi, N);
    k_count<<<(E + B - 1) / B, B, 0, stream>>>(dst, E, degi);
    k_scan1<<<nb, 256, 0, stream>>>(degi, rowptr, blocksum, N);
    k_scan2<<<1, 256, 0, stream>>>(blocksum, nb);
    k_scan3<<<nb, 256, 0, stream>>>(rowptr, blocksum, degi, cursor, dinv, N);
    k_fill<<<(E + B - 1) / B, B, 0, stream>>>(src, dst, E, cursor, col);

    // Layer 1: 128 -> 128
    k_gemm<128, 128, 16, 0, float><<<(N + 15) / 16, 256, 0, stream>>>(x, W1, dinv, nullptr, hs1, N);
    k_agg<128, __hip_bfloat16><<<(N + 3) / 4, 256, 0, stream>>>(rowptr, col, hs1, dinv, b1, h1, N);

    // Layer 2: 128 -> 64 (input h1 bf16)
    k_gemm<128, 64, 16, 0, __hip_bfloat16><<<(N + 15) / 16, 256, 0, stream>>>(h1, W2, dinv, nullptr, hs2, N);
    k_agg<64, float><<<(N + 3) / 4, 256, 0, stream>>>(rowptr, col, hs2, dinv, b2, h2, N);

    // FC head: 64 -> 64
    k_gemm<64, 64, 16, 1, float><<<(N + 15) / 16, 256, 0, stream>>>(h2, fcW, nullptr, fcb, out, N);
}